// Round 10
// baseline (456.106 us; speedup 1.0000x reference)
//
#include <hip/hip_runtime.h>
#include <hip/hip_bf16.h>

#define EPSV 1e-5f

constexpr int B_ = 16, C_ = 256;
constexpr int OHW_ = 49 * 49;          // 2401
constexpr int NTOT = 256 * 16 * 16;    // 65536
constexpr int GROUPS = 32, CPERG = 8;

typedef short bf16x8 __attribute__((ext_vector_type(8)));
typedef float f32x4 __attribute__((ext_vector_type(4)));

// ---------------- workspace layout (float offsets) ----------------
constexpr size_t OFF_S1 = 0;                               // conv1 out, 16*256*4096 f32
constexpr size_t SZ_S1  = (size_t)16 * 256 * 4096;
constexpr size_t OFF_T2 = OFF_S1 + SZ_S1;                  // conv2 out (bn'd in place)
constexpr size_t SZ_T2  = (size_t)16 * 256 * 256;
constexpr size_t OFF_ST = OFF_T2 + SZ_T2;                  // stats block (2048 f)
constexpr size_t OFF_Z  = OFF_ST + 2048;                   // [2][16][4096] z, z2
constexpr size_t OFF_C  = OFF_Z + 131072;                  // overlaid big region
constexpr size_t SPC_BYTES = (size_t)16 * 66 * 66 * 256 * 2;
constexpr size_t TPC_BYTES = (size_t)16 * 18 * 18 * 256 * 2;
constexpr size_t WR_BYTES  = (size_t)9 * 256 * 256 * 2;
constexpr size_t CPOFF = 0;
constexpr size_t NCOFF = CPOFF + (size_t)GROUPS * 16 * OHW_;
constexpr size_t SATOFF = NCOFF + (size_t)16 * OHW_;

// ---------------- async global->LDS 16B ----------------
__device__ __forceinline__ void gload_lds16(const void* g, void* l) {
    __builtin_amdgcn_global_load_lds((const __attribute__((address_space(1))) unsigned int*)g,
                                     (__attribute__((address_space(3))) unsigned int*)l,
                                     16, 0, 0);
}

// ---------------- pad + NCHW->NHWC + bf16 + weight reorg, merged ----------------
template<int W>
__device__ __forceinline__ void pad_body(int bid, const float* __restrict__ in,
                                         __hip_bfloat16* __restrict__ outp, float* tile)
{
    constexpr int PW = W + 2;
    int icg = bid & 3; bid >>= 2;
    int yp = bid % PW; bid /= PW;
    int b = bid;
    int ic0 = icg * 64;
    int tid = threadIdx.x;
    bool interior = (yp >= 1 && yp <= W);
    if (interior) {
        int y = yp - 1;
        for (int idx = tid; idx < 64 * W; idx += 256) {
            int i = idx / W, x = idx % W;
            tile[i * (W + 1) + x] = in[(((size_t)(b * C_ + ic0 + i)) * W + y) * W + x];
        }
    }
    __syncthreads();
    for (int idx = tid; idx < PW * 16; idx += 256) {
        int xp = idx >> 4, i4 = idx & 15;
        ushort4 v = make_ushort4(0, 0, 0, 0);
        if (interior && xp >= 1 && xp <= W) {
            #pragma unroll
            for (int k = 0; k < 4; ++k) {
                __hip_bfloat16 h = __float2bfloat16(tile[(i4 * 4 + k) * (W + 1) + xp - 1]);
                reinterpret_cast<unsigned short*>(&v)[k] = *reinterpret_cast<unsigned short*>(&h);
            }
        }
        *reinterpret_cast<ushort4*>(&outp[(((size_t)(b * PW) + yp) * PW + xp) * 256 + ic0 + i4 * 4]) = v;
    }
}

__global__ __launch_bounds__(256)
void pad_all(const float* __restrict__ s, const float* __restrict__ t,
             __hip_bfloat16* __restrict__ SPc, __hip_bfloat16* __restrict__ TPc,
             const float* __restrict__ w1, const float* __restrict__ w2,
             __hip_bfloat16* __restrict__ wr1, __hip_bfloat16* __restrict__ wr2)
{
    __shared__ float tile[64 * 65];
    constexpr int NP1 = 16 * 66 * 4, NP2 = 16 * 18 * 4;
    int bid = blockIdx.x;
    if (bid < NP1) { pad_body<64>(bid, s, SPc, tile); return; }
    bid -= NP1;
    if (bid < NP2) { pad_body<16>(bid, t, TPc, tile); return; }
    bid -= NP2;
    const float* w = (bid < 256) ? w1 : w2;
    __hip_bfloat16* wr = (bid < 256) ? wr1 : wr2;
    int idx = (bid & 255) * 256 + threadIdx.x;
    const float* src = w + (size_t)idx * 9;
    #pragma unroll
    for (int t_ = 0; t_ < 9; ++t_)
        wr[(size_t)t_ * 65536 + idx] = __float2bfloat16(src[t_]);
}

// ---------------- conv: 256x256x64 deep-pipelined 4-phase/K-tile MFMA ----------------
// LDS 128KB: A[2 slot][2 half][128 rows][8 gran x 16B], B same at +64KB.
// Phase quadrant (mh,nh) reads exactly A-half mh, B-half nh (wave-M interleaved 64-chunks).
template<int W>
__device__ __forceinline__ void conv8p_body(
    int bb, int nt,
    const __hip_bfloat16* __restrict__ SPc, const __hip_bfloat16* __restrict__ Wr,
    const float* __restrict__ bias, float* __restrict__ out,
    float* __restrict__ csum, float* __restrict__ csq, char* smem)
{
    constexpr int PW = W + 2;
    constexpr int NPIX = W * W;
    constexpr int LOG2W = (W == 64) ? 6 : 4;
    int tid = threadIdx.x;
    int lane = tid & 63;
    int wv = tid >> 6;
    int wm = wv >> 2, wn = wv & 3;       // 2 x 4 wave grid
    int rA = lane & 15, colb = lane >> 4;

    f32x4 acc[8][4];
    #pragma unroll
    for (int i = 0; i < 8; ++i)
        #pragma unroll
        for (int j = 0; j < 4; ++j)
            #pragma unroll
            for (int r = 0; r < 4; ++r) acc[i][j][r] = 0.f;

    // staging thread-consts: slot si -> (row, granule); source pre-swizzled g^(row&7)
    int row_s[2], gs_s[2];
    #pragma unroll
    for (int k = 0; k < 2; ++k) {
        int si = tid + k * 512;
        int row = si >> 3, g = si & 7;
        row_s[k] = row; gs_s[k] = g ^ (row & 7);
    }

    auto Abase = [&](int s, int half) { return smem + s * 32768 + half * 16384; };
    auto Bbase = [&](int s, int half) { return smem + 65536 + s * 32768 + half * 16384; };

    auto stageA = [&](int s, int half, int kt) {
        int tap = kt >> 2, icc = kt & 3;
        char* dst = Abase(s, half);
        #pragma unroll
        for (int k = 0; k < 2; ++k) {
            const __hip_bfloat16* src =
                Wr + ((size_t)(tap * 256 + half * 128 + row_s[k])) * 256 + icc * 64 + gs_s[k] * 8;
            gload_lds16(src, dst + (tid + k * 512) * 16);
        }
    };
    auto stageB = [&](int s, int half, int kt) {
        int tap = kt >> 2, icc = kt & 3;
        int dy = tap / 3, dx = tap - dy * 3;
        char* dst = Bbase(s, half);
        #pragma unroll
        for (int k = 0; k < 2; ++k) {
            int row = row_s[k];
            int gy = nt * (256 >> LOG2W) + ((half * 128 + row) >> LOG2W) + dy;
            int gx = (row & (W - 1)) + dx;
            const __hip_bfloat16* src =
                SPc + (((size_t)(bb * PW + gy)) * PW + gx) * 256 + icc * 64 + gs_s[k] * 8;
            gload_lds16(src, dst + (tid + k * 512) * 16);
        }
    };

    bf16x8 a[4][2];          // current mh's A frags
    bf16x8 bfr[2][2][2];     // [nh][ni][ks] B frags, live across 2 phases
    auto loadA = [&](int s, int half) {
        const bf16x8* Av = (const bf16x8*)Abase(s, half);
        #pragma unroll
        for (int mi = 0; mi < 4; ++mi) {
            int rl = wm * 64 + mi * 16 + rA;
            #pragma unroll
            for (int ks = 0; ks < 2; ++ks)
                a[mi][ks] = Av[rl * 8 + ((ks * 4 + colb) ^ (rA & 7))];
        }
    };
    auto loadB0 = [&](int s) {
        const bf16x8* Bv = (const bf16x8*)Bbase(s, 0);
        #pragma unroll
        for (int ni = 0; ni < 2; ++ni) {
            int rl = wn * 32 + ni * 16 + rA;
            #pragma unroll
            for (int ks = 0; ks < 2; ++ks)
                bfr[0][ni][ks] = Bv[rl * 8 + ((ks * 4 + colb) ^ (rA & 7))];
        }
    };
    auto loadB1 = [&](int s) {
        const bf16x8* Bv = (const bf16x8*)Bbase(s, 1);
        #pragma unroll
        for (int ni = 0; ni < 2; ++ni) {
            int rl = wn * 32 + ni * 16 + rA;
            #pragma unroll
            for (int ks = 0; ks < 2; ++ks)
                bfr[1][ni][ks] = Bv[rl * 8 + ((ks * 4 + colb) ^ (rA & 7))];
        }
    };

    #define QUAD(mh, nh)                                                            \
        __builtin_amdgcn_s_setprio(1);                                              \
        _Pragma("unroll")                                                           \
        for (int mi = 0; mi < 4; ++mi)                                              \
            _Pragma("unroll")                                                       \
            for (int ni = 0; ni < 2; ++ni)                                          \
                _Pragma("unroll")                                                   \
                for (int ks = 0; ks < 2; ++ks)                                      \
                    acc[(mh)*4+mi][(nh)*2+ni] = __builtin_amdgcn_mfma_f32_16x16x32_bf16( \
                        a[mi][ks], bfr[nh][ni][ks], acc[(mh)*4+mi][(nh)*2+ni], 0,0,0);   \
        __builtin_amdgcn_s_setprio(0);

    // prologue: stage kt0 (order A0,B0,B1,A1), wait A0+B0
    stageA(0, 0, 0); stageB(0, 0, 0); stageB(0, 1, 0); stageA(0, 1, 0);
    asm volatile("s_waitcnt vmcnt(4)" ::: "memory");
    asm volatile("s_barrier" ::: "memory");

    for (int kt = 0; kt < 36; ++kt) {
        int s = kt & 1, sn = s ^ 1;
        bool st = (kt < 35);
        int nkt = kt + 1;
        // P0 (0,0): reads A-h0,B-h0; stage A0'; wait covers B1(cur)
        loadA(s, 0); loadB0(s);
        if (st) {
            stageA(sn, 0, nkt);
            asm volatile("s_waitcnt vmcnt(4)" ::: "memory");
        } else {
            asm volatile("s_waitcnt vmcnt(2)" ::: "memory");
        }
        asm volatile("s_barrier" ::: "memory");
        QUAD(0, 0)
        // P1 (0,1): reads B-h1; stage B0'; wait covers A1(cur)
        loadB1(s);
        if (st) {
            stageB(sn, 0, nkt);
            asm volatile("s_waitcnt vmcnt(4)" ::: "memory");
        } else {
            asm volatile("s_waitcnt vmcnt(0)" ::: "memory");
        }
        asm volatile("s_barrier" ::: "memory");
        QUAD(0, 1)
        // P2 (1,0): reads A-h1 (B-h0 from regs); stage B1'; no wait
        loadA(s, 1);
        if (st) stageB(sn, 1, nkt);
        asm volatile("s_barrier" ::: "memory");
        QUAD(1, 0)
        // P3 (1,1): all from regs; stage A1'; wait covers A0',B0'
        if (st) {
            stageA(sn, 1, nkt);
            asm volatile("s_waitcnt vmcnt(4)" ::: "memory");
        }
        asm volatile("s_barrier" ::: "memory");
        QUAD(1, 1)
    }
    #undef QUAD

    // epilogue: +bias, store NCHW fp32, fused channel stats
    int p0g = nt * 256;
    #pragma unroll
    for (int mi = 0; mi < 8; ++mi) {
        int oc = (mi >> 2) * 128 + wm * 64 + (mi & 3) * 16 + colb * 4;
        #pragma unroll
        for (int r = 0; r < 4; ++r) {
            int ocr = oc + r;
            float bv = bias[ocr];
            float* orow = out + ((size_t)(bb * C_ + ocr)) * NPIX;
            float s_oc = 0.f, q_oc = 0.f;
            #pragma unroll
            for (int nj = 0; nj < 4; ++nj) {
                int px = p0g + (nj >> 1) * 128 + wn * 32 + (nj & 1) * 16 + rA;
                float v = acc[mi][nj][r] + bv;
                orow[px] = v;
                s_oc += v; q_oc += v * v;
            }
            #pragma unroll
            for (int m_ = 1; m_ < 16; m_ <<= 1) {
                s_oc += __shfl_xor(s_oc, m_);
                q_oc += __shfl_xor(q_oc, m_);
            }
            if (rA == 0) {
                atomicAdd(&csum[ocr], s_oc);
                atomicAdd(&csq[ocr], q_oc);
            }
        }
    }
}

__global__ __launch_bounds__(512, 2)
void conv8p(const __hip_bfloat16* __restrict__ SPc, const __hip_bfloat16* __restrict__ Wr1,
            const float* __restrict__ b1, float* __restrict__ S1,
            float* __restrict__ CHS1, float* __restrict__ CHQ1,
            const __hip_bfloat16* __restrict__ TPc, const __hip_bfloat16* __restrict__ Wr2,
            const float* __restrict__ b2, float* __restrict__ T2,
            float* __restrict__ CHS2, float* __restrict__ CHQ2)
{
    extern __shared__ char smem[];
    int bid = blockIdx.x;
    if (bid < 16) {
        conv8p_body<16>(bid, 0, TPc, Wr2, b2, T2, CHS2, CHQ2, smem);
    } else {
        int l = bid - 16;
        int logical = (l & 7) * 32 + (l >> 3);   // bijective XCD remap (256 % 8 == 0)
        conv8p_body<64>(logical >> 4, logical & 15, SPc, Wr1, b1, S1, CHS1, CHQ1, smem);
    }
}

// ---------------- block reduce helper ----------------
__device__ inline void blk_reduce2(float& a, float& q, int tid) {
    #pragma unroll
    for (int off = 32; off > 0; off >>= 1) {
        a += __shfl_down(a, off);
        q += __shfl_down(q, off);
    }
    __shared__ float ra[4], rq[4];
    if ((tid & 63) == 0) { ra[tid >> 6] = a; rq[tid >> 6] = q; }
    __syncthreads();
    if (tid == 0) { a = ra[0] + ra[1] + ra[2] + ra[3]; q = rq[0] + rq[1] + rq[2] + rq[3]; }
}

// ---------------- BN2 normalize + template stats ----------------
__global__ __launch_bounds__(256)
void bn_t2_stats(float* __restrict__ T2, const float* __restrict__ csum,
                 const float* __restrict__ csq, const float* __restrict__ g2,
                 const float* __restrict__ be2, float* __restrict__ tmean,
                 float* __restrict__ ttstd)
{
    __shared__ float SC[256], SH[256];
    int b = blockIdx.x, tid = threadIdx.x;
    {
        float m = csum[tid] * (1.f / 4096.f);
        float v = csq[tid] * (1.f / 4096.f) - m * m;
        float sc = rsqrtf(v + EPSV) * g2[tid];
        SC[tid] = sc; SH[tid] = be2[tid] - m * sc;
    }
    __syncthreads();
    float4* p = reinterpret_cast<float4*>(T2 + (size_t)b * NTOT);
    float s = 0.f, q = 0.f;
    for (int i4 = tid; i4 < NTOT / 4; i4 += 256) {
        int c = i4 >> 6;
        float sc = SC[c], sh = SH[c];
        float4 v = p[i4];
        v.x = v.x * sc + sh; v.y = v.y * sc + sh;
        v.z = v.z * sc + sh; v.w = v.w * sc + sh;
        s += v.x + v.y + v.z + v.w;
        q += v.x * v.x + v.y * v.y + v.z * v.z + v.w * v.w;
        p[i4] = v;
    }
    blk_reduce2(s, q, tid);
    if (tid == 0) {
        float m = s / (float)NTOT;
        tmean[b] = m;
        ttstd[b] = sqrtf(fmaxf(q - (float)NTOT * m * m, 0.f) / (float)(NTOT - 1));
    }
}

// ---------------- cross-correlation + fused z/z2 partials ----------------
__global__ __launch_bounds__(256, 2)
void cross_v3(const float* __restrict__ s1, const float* __restrict__ t2,
              const float* __restrict__ csum, const float* __restrict__ csq,
              const float* __restrict__ g1, const float* __restrict__ be1,
              float* __restrict__ cpart, float* __restrict__ z)
{
    __shared__ float4 spl4[1024];
    __shared__ float tpl[256];
    __shared__ float red[4][64][49];

    int g = blockIdx.x & (GROUPS - 1);
    int b = blockIdx.x / GROUPS;
    int tid = threadIdx.x;
    int phase = tid >> 6;
    int lane = tid & 63;
    int i = lane;
    int i_ld = i < 49 ? i : 48;

    float acc[49];
    #pragma unroll
    for (int j = 0; j < 49; ++j) acc[j] = 0.f;
    float4 zs[4], zq[4];
    #pragma unroll
    for (int k = 0; k < 4; ++k) {
        zs[k] = make_float4(0.f, 0.f, 0.f, 0.f);
        zq[k] = make_float4(0.f, 0.f, 0.f, 0.f);
    }

    #pragma unroll 1
    for (int cc = 0; cc < CPERG; ++cc) {
        int c = g * CPERG + cc;
        float m = csum[c] * (1.f / 65536.f);
        float v = csq[c] * (1.f / 65536.f) - m * m;
        float sc = rsqrtf(v + EPSV) * g1[c];
        float sh = be1[c] - m * sc;
        __syncthreads();
        const float4* sp4 = reinterpret_cast<const float4*>(s1 + ((size_t)(b * C_ + c)) * 4096);
        #pragma unroll
        for (int k = 0; k < 4; ++k) {
            int gidx = tid + k * 256;
            float4 val = sp4[gidx];
            val.x = val.x * sc + sh; val.y = val.y * sc + sh;
            val.z = val.z * sc + sh; val.w = val.w * sc + sh;
            zs[k].x += val.x; zs[k].y += val.y; zs[k].z += val.z; zs[k].w += val.w;
            zq[k].x += val.x * val.x; zq[k].y += val.y * val.y;
            zq[k].z += val.z * val.z; zq[k].w += val.w * val.w;
            int row = gidx >> 4, jg = gidx & 15;
            spl4[row * 16 + (jg ^ (row & 7))] = val;
        }
        tpl[tid] = t2[((size_t)(b * C_ + c)) * 256 + tid];
        __syncthreads();
        #pragma unroll 1
        for (int tyl = 0; tyl < 4; ++tyl) {
            int ty = phase * 4 + tyl;
            int row = i_ld + ty;
            float r_[64];
            #pragma unroll
            for (int jg = 0; jg < 16; ++jg) {
                float4 v4 = spl4[row * 16 + (jg ^ (row & 7))];
                r_[jg * 4 + 0] = v4.x; r_[jg * 4 + 1] = v4.y;
                r_[jg * 4 + 2] = v4.z; r_[jg * 4 + 3] = v4.w;
            }
            float tt[16];
            const float4* tp4 = reinterpret_cast<const float4*>(&tpl[ty * 16]);
            #pragma unroll
            for (int k = 0; k < 4; ++k) {
                float4 tv = tp4[k];
                tt[k * 4 + 0] = tv.x; tt[k * 4 + 1] = tv.y;
                tt[k * 4 + 2] = tv.z; tt[k * 4 + 3] = tv.w;
            }
            #pragma unroll
            for (int tx = 0; tx < 16; ++tx)
                #pragma unroll
                for (int j = 0; j < 49; ++j)
                    acc[j] += tt[tx] * r_[j + tx];
        }
    }
    #pragma unroll
    for (int k = 0; k < 4; ++k) {
        int pxb = (tid + k * 256) * 4;
        float* zb  = z + (size_t)b * 4096 + pxb;
        float* z2b = z + 65536 + (size_t)b * 4096 + pxb;
        atomicAdd(&zb[0], zs[k].x);  atomicAdd(&zb[1], zs[k].y);
        atomicAdd(&zb[2], zs[k].z);  atomicAdd(&zb[3], zs[k].w);
        atomicAdd(&z2b[0], zq[k].x); atomicAdd(&z2b[1], zq[k].y);
        atomicAdd(&z2b[2], zq[k].z); atomicAdd(&z2b[3], zq[k].w);
    }
    __syncthreads();
    if (i < 49) {
        #pragma unroll
        for (int j = 0; j < 49; ++j) red[phase][i][j] = acc[j];
    }
    __syncthreads();
    float* dst = cpart + ((size_t)(g * B_ + b)) * OHW_;
    for (int e = tid; e < OHW_; e += 256) {
        int ii = e / 49, jj = e - ii * 49;
        dst[e] = red[0][ii][jj] + red[1][ii][jj] + red[2][ii][jj] + red[3][ii][jj];
    }
}

// ---------------- integral images ----------------
__global__ __launch_bounds__(256)
void sat_kernel(const float* __restrict__ zin, float* __restrict__ sat)
{
    __shared__ float t[65][66];
    int pl = blockIdx.x;
    int tid = threadIdx.x;
    const float* src = zin + (size_t)pl * 4096;
    for (int idx = tid; idx < 4096; idx += 256) {
        int y = idx >> 6, x = idx & 63;
        t[y + 1][x + 1] = src[idx];
    }
    for (int idx = tid; idx < 65; idx += 256) { t[0][idx] = 0.f; t[idx][0] = 0.f; }
    __syncthreads();
    if (tid < 64) {
        float run = 0.f;
        for (int x = 1; x <= 64; ++x) { run += t[tid + 1][x]; t[tid + 1][x] = run; }
    }
    __syncthreads();
    if (tid < 64) {
        float run = 0.f;
        for (int y = 1; y <= 64; ++y) { run += t[y][tid + 1]; t[y][tid + 1] = run; }
    }
    __syncthreads();
    float* dst = sat + (size_t)pl * 4225;
    for (int idx = tid; idx < 4225; idx += 256) {
        int r = idx / 65, c = idx % 65;
        dst[idx] = t[r][c];
    }
}

// ---------------- NCC assembly via SAT + global stats ----------------
__global__ __launch_bounds__(256)
void ncc_kernel(const float* __restrict__ cpart, const float* __restrict__ sat,
                const float* __restrict__ tmean, const float* __restrict__ ttstd,
                float* __restrict__ ncc, float* __restrict__ s3)
{
    int idx = blockIdx.x * 256 + threadIdx.x;
    float val = 0.f;
    if (idx < B_ * OHW_) {
        int b = idx / OHW_, r = idx - b * OHW_;
        int i = r / 49, j = r - i * 49;
        float cr = 0.f;
        #pragma unroll 4
        for (int g = 0; g < GROUPS; ++g) cr += cpart[((size_t)(g * B_ + b)) * OHW_ + r];
        const float* sz = sat + (size_t)b * 4225;
        const float* sq = sat + (size_t)(16 + b) * 4225;
        int a00 = i * 65 + j, a01 = i * 65 + j + 16;
        int a10 = (i + 16) * 65 + j, a11 = (i + 16) * 65 + j + 16;
        float wsum = sz[a11] - sz[a01] - sz[a10] + sz[a00];
        float wq   = sq[a11] - sq[a01] - sq[a10] + sq[a00];
        float crosst = cr - tmean[b] * wsum;
        float ssvar = fmaxf(wq - wsum * wsum * (1.f / 65536.f), 0.f) * (1.f / 65535.f);
        float ssstd = sqrtf(ssvar);
        val = crosst / (65536.f * ttstd[b] * ssstd);
        ncc[idx] = val;
    }
    float s = val, q = val * val;
    blk_reduce2(s, q, threadIdx.x);
    if (threadIdx.x == 0) { atomicAdd(&s3[0], s); atomicAdd(&s3[1], q); }
}

// ---------------- conv3+BN3+relu+conv4 ----------------
__global__ __launch_bounds__(256)
void final_kernel(const float* __restrict__ ncc, const float* __restrict__ s3,
                  const float* __restrict__ w3, const float* __restrict__ b3,
                  const float* __restrict__ g3, const float* __restrict__ be3,
                  const float* __restrict__ w4, const float* __restrict__ b4,
                  float* __restrict__ out)
{
    int idx = blockIdx.x * 256 + threadIdx.x;
    if (idx >= B_ * OHW_) return;
    constexpr float M = (float)(B_ * OHW_);
    float mn = s3[0] / M;
    float vn = s3[1] / M - mn * mn;
    float W3 = w3[0], B3 = b3[0];
    float my = W3 * mn + B3;
    float vy = W3 * W3 * vn;
    float sc = rsqrtf(vy + EPSV) * g3[0];
    float y = (W3 * ncc[idx] + B3 - my) * sc + be3[0];
    float h = fmaxf(y, 0.f);
    int b = idx / OHW_, r = idx - b * OHW_;
    out[((size_t)(b * 2 + 0)) * OHW_ + r] = h * w4[0] + b4[0];
    out[((size_t)(b * 2 + 1)) * OHW_ + r] = h * w4[1] + b4[1];
}

extern "C" void kernel_launch(void* const* d_in, const int* in_sizes, int n_in,
                              void* d_out, int out_size, void* d_ws, size_t ws_size,
                              hipStream_t stream)
{
    const float* s   = (const float*)d_in[0];
    const float* t   = (const float*)d_in[1];
    const float* w1  = (const float*)d_in[2];
    const float* b1  = (const float*)d_in[3];
    const float* g1  = (const float*)d_in[4];
    const float* be1 = (const float*)d_in[5];
    const float* w2  = (const float*)d_in[6];
    const float* b2  = (const float*)d_in[7];
    const float* g2  = (const float*)d_in[8];
    const float* be2 = (const float*)d_in[9];
    const float* w3  = (const float*)d_in[10];
    const float* b3  = (const float*)d_in[11];
    const float* g3  = (const float*)d_in[12];
    const float* be3 = (const float*)d_in[13];
    const float* w4  = (const float*)d_in[14];
    const float* b4  = (const float*)d_in[15];

    float* ws = (float*)d_ws;
    float* S1 = ws + OFF_S1;
    float* T2 = ws + OFF_T2;
    float* ST = ws + OFF_ST;
    float* CHS1 = ST + 0;
    float* CHQ1 = ST + 256;
    float* CHS2 = ST + 512;
    float* CHQ2 = ST + 768;
    float* S3   = ST + 1024;
    float* TM   = ST + 1040;
    float* TSD  = ST + 1056;
    float* Z    = ws + OFF_Z;

    char* Cb = (char*)(ws + OFF_C);
    __hip_bfloat16* SPc = (__hip_bfloat16*)Cb;
    __hip_bfloat16* TPc = (__hip_bfloat16*)(Cb + SPC_BYTES);
    __hip_bfloat16* Wr1 = (__hip_bfloat16*)(Cb + SPC_BYTES + TPC_BYTES);
    __hip_bfloat16* Wr2 = (__hip_bfloat16*)(Cb + SPC_BYTES + TPC_BYTES + WR_BYTES);
    float* Cf = (float*)Cb;
    float* CP  = Cf + CPOFF;
    float* NC  = Cf + NCOFF;
    float* SAT = Cf + SATOFF;

    hipMemsetAsync(ST, 0, (2048 + 131072) * sizeof(float), stream);

    pad_all<<<dim3(16 * 66 * 4 + 16 * 18 * 4 + 512), dim3(256), 0, stream>>>(
        s, t, SPc, TPc, w1, w2, Wr1, Wr2);

    (void)hipFuncSetAttribute((const void*)conv8p,
                              hipFuncAttributeMaxDynamicSharedMemorySize, 131072);
    conv8p<<<dim3(16 + 256), dim3(512), 131072, stream>>>(SPc, Wr1, b1, S1, CHS1, CHQ1,
                                                          TPc, Wr2, b2, T2, CHS2, CHQ2);

    bn_t2_stats<<<dim3(16), dim3(256), 0, stream>>>(T2, CHS2, CHQ2, g2, be2, TM, TSD);

    cross_v3<<<dim3(16 * GROUPS), dim3(256), 0, stream>>>(S1, T2, CHS1, CHQ1, g1, be1, CP, Z);
    sat_kernel<<<dim3(32), dim3(256), 0, stream>>>(Z, SAT);
    ncc_kernel<<<dim3(151), dim3(256), 0, stream>>>(CP, SAT, TM, TSD, NC, S3);
    final_kernel<<<dim3(151), dim3(256), 0, stream>>>(NC, S3, w3, b3, g3, be3, w4, b4, (float*)d_out);
}